// Round 1
// baseline (144.919 us; speedup 1.0000x reference)
//
#include <hip/hip_runtime.h>

typedef unsigned short u16;
typedef u16 u16x4 __attribute__((ext_vector_type(4)));
typedef u16 u16x8 __attribute__((ext_vector_type(8)));
typedef __bf16 bf16x8 __attribute__((ext_vector_type(8)));
typedef float f32x4 __attribute__((ext_vector_type(4)));

static __device__ __forceinline__ u16 f2bf(float f) {
  unsigned u = __builtin_bit_cast(unsigned, f);
  u += 0x7FFFu + ((u >> 16) & 1u);   // RTNE
  return (u16)(u >> 16);
}

// ---------------- x f32 -> bf16 ----------------
__global__ __launch_bounds__(256) void cvt_x_kernel(const float* __restrict__ in,
                                                    u16* __restrict__ out) {
  int i = blockIdx.x * 256 + threadIdx.x;          // 8 elems per thread
  const float4* p = reinterpret_cast<const float4*>(in) + (size_t)i * 2;
  float4 a = p[0], b = p[1];
  u16x8 o;
  o[0] = f2bf(a.x); o[1] = f2bf(a.y); o[2] = f2bf(a.z); o[3] = f2bf(a.w);
  o[4] = f2bf(b.x); o[5] = f2bf(b.y); o[6] = f2bf(b.z); o[7] = f2bf(b.w);
  reinterpret_cast<u16x8*>(out)[i] = o;
}

// ---------------- W [768][2304] f32 -> WbT [2304][768] bf16 ----------------
__global__ __launch_bounds__(256) void cvt_wT_kernel(const float* __restrict__ W,
                                                     u16* __restrict__ WT) {
  int n  = blockIdx.x * 256 + threadIdx.x;   // 0..2303 (gridDim.x = 9)
  int k0 = blockIdx.y * 4;                   // gridDim.y = 192
  u16x4 o;
#pragma unroll
  for (int j = 0; j < 4; ++j) o[j] = f2bf(W[(size_t)(k0 + j) * 2304 + n]);
  *reinterpret_cast<u16x4*>(WT + (size_t)n * 768 + k0) = o;
}

// ---------------- QKV GEMM: [8192x768] @ [768x2304] + bias ----------------
// writes q[bh][t][d], k[bh][t][d], vT[bh][d][t]  (all bf16)
#define BM 128
#define BN 128
#define BK 32
#define LDP 40   // padded LDS row stride (elems): 80B -> 16B aligned, low conflicts

__global__ __launch_bounds__(256) void gemm_qkv_kernel(
    const u16* __restrict__ A, const u16* __restrict__ Bt,
    const float* __restrict__ bias,
    u16* __restrict__ qb, u16* __restrict__ kb, u16* __restrict__ vTb) {
  __shared__ __align__(16) u16 as[BM * LDP];
  __shared__ __align__(16) u16 bs[BN * LDP];
  const int K = 768;
  int tid = threadIdx.x;
  int lane = tid & 63;
  int wave = tid >> 6;
  int m0 = blockIdx.x * BM;        // gridDim.x = 64
  int n0 = blockIdx.y * BN;        // gridDim.y = 18
  int wm = (wave >> 1) * 64;
  int wn = (wave & 1) * 64;
  int srow = tid >> 2;             // 0..63
  int scol = (tid & 3) * 8;        // 0,8,16,24
  int l16 = lane & 15, g = lane >> 4;

  f32x4 acc[4][4];
#pragma unroll
  for (int mi = 0; mi < 4; ++mi)
#pragma unroll
    for (int ni = 0; ni < 4; ++ni) acc[mi][ni] = (f32x4){0.f, 0.f, 0.f, 0.f};

  for (int k0 = 0; k0 < K; k0 += BK) {
    u16x8 av0 = *reinterpret_cast<const u16x8*>(A + (size_t)(m0 + srow) * K + k0 + scol);
    u16x8 av1 = *reinterpret_cast<const u16x8*>(A + (size_t)(m0 + srow + 64) * K + k0 + scol);
    u16x8 bv0 = *reinterpret_cast<const u16x8*>(Bt + (size_t)(n0 + srow) * K + k0 + scol);
    u16x8 bv1 = *reinterpret_cast<const u16x8*>(Bt + (size_t)(n0 + srow + 64) * K + k0 + scol);
    __syncthreads();   // protect previous iteration's LDS reads
    *reinterpret_cast<u16x8*>(as + srow * LDP + scol) = av0;
    *reinterpret_cast<u16x8*>(as + (srow + 64) * LDP + scol) = av1;
    *reinterpret_cast<u16x8*>(bs + srow * LDP + scol) = bv0;
    *reinterpret_cast<u16x8*>(bs + (srow + 64) * LDP + scol) = bv1;
    __syncthreads();

    bf16x8 af[4], bf[4];
#pragma unroll
    for (int mi = 0; mi < 4; ++mi)
      af[mi] = __builtin_bit_cast(bf16x8,
          *reinterpret_cast<const u16x8*>(as + (wm + mi * 16 + l16) * LDP + g * 8));
#pragma unroll
    for (int ni = 0; ni < 4; ++ni)
      bf[ni] = __builtin_bit_cast(bf16x8,
          *reinterpret_cast<const u16x8*>(bs + (wn + ni * 16 + l16) * LDP + g * 8));
#pragma unroll
    for (int mi = 0; mi < 4; ++mi)
#pragma unroll
      for (int ni = 0; ni < 4; ++ni)
        acc[mi][ni] = __builtin_amdgcn_mfma_f32_16x16x32_bf16(af[mi], bf[ni], acc[mi][ni], 0, 0, 0);
  }

  // epilogue: bias + scatter to q/k/vT (bf16)
  int tbase = m0 & 1023;
  int b = m0 >> 10;
  int g4 = g * 4;
#pragma unroll
  for (int ni = 0; ni < 4; ++ni) {
    int n = n0 + wn + ni * 16 + l16;
    float bv = bias[n];
    int region = n / 768;
    int c = n - region * 768;
    int h = c >> 6, d = c & 63;
    int bh = b * 12 + h;
#pragma unroll
    for (int mi = 0; mi < 4; ++mi) {
      int t0 = tbase + wm + mi * 16 + g4;
      if (region == 2) {
        u16x4 pv;
#pragma unroll
        for (int r = 0; r < 4; ++r) pv[r] = f2bf(acc[mi][ni][r] + bv);
        *reinterpret_cast<u16x4*>(vTb + ((size_t)bh * 64 + d) * 1024 + t0) = pv;
      } else {
        u16* dst = (region == 0) ? qb : kb;
#pragma unroll
        for (int r = 0; r < 4; ++r)
          dst[((size_t)bh * 1024 + t0 + r) * 64 + d] = f2bf(acc[mi][ni][r] + bv);
      }
    }
  }
}

// ---------------- causal relu attention ----------------
// y[b,h,q,:] = sum_{k<=q} relu(scale * q.k) * v[k]
__global__ __launch_bounds__(256) void attn_kernel(
    const u16* __restrict__ qb, const u16* __restrict__ kb,
    const u16* __restrict__ vTb, float* __restrict__ out) {
  __shared__ __align__(16) u16 plds[4][32 * 40];
  int lane = threadIdx.x & 63;
  int wave = threadIdx.x >> 6;
  int bh = blockIdx.x;                   // 0..95
  int q0 = blockIdx.y * 128 + wave * 32; // wave-private 32 q-rows
  int b = bh / 12, h = bh - b * 12;
  const u16* Q  = qb  + (size_t)bh * 65536;
  const u16* Kp = kb  + (size_t)bh * 65536;
  const u16* Vt = vTb + (size_t)bh * 65536;
  int l16 = lane & 15, g = lane >> 4;
  u16* pw = &plds[wave][0];

  bf16x8 qf[2][2];
#pragma unroll
  for (int mi = 0; mi < 2; ++mi)
#pragma unroll
    for (int ks = 0; ks < 2; ++ks)
      qf[mi][ks] = __builtin_bit_cast(bf16x8,
          *reinterpret_cast<const u16x8*>(Q + (q0 + mi * 16 + l16) * 64 + ks * 32 + g * 8));

  f32x4 y[2][4];
#pragma unroll
  for (int mi = 0; mi < 2; ++mi)
#pragma unroll
    for (int ni = 0; ni < 4; ++ni) y[mi][ni] = (f32x4){0.f, 0.f, 0.f, 0.f};

  int ktmax = q0 >> 5;
  for (int kt = 0; kt <= ktmax; ++kt) {
    int kbase = kt << 5;
    f32x4 s[2][2];
#pragma unroll
    for (int mi = 0; mi < 2; ++mi)
#pragma unroll
      for (int nj = 0; nj < 2; ++nj) s[mi][nj] = (f32x4){0.f, 0.f, 0.f, 0.f};

#pragma unroll
    for (int ks = 0; ks < 2; ++ks) {
#pragma unroll
      for (int nj = 0; nj < 2; ++nj) {
        bf16x8 kf = __builtin_bit_cast(bf16x8,
            *reinterpret_cast<const u16x8*>(Kp + (kbase + nj * 16 + l16) * 64 + ks * 32 + g * 8));
#pragma unroll
        for (int mi = 0; mi < 2; ++mi)
          s[mi][nj] = __builtin_amdgcn_mfma_f32_16x16x32_bf16(qf[mi][ks], kf, s[mi][nj], 0, 0, 0);
      }
    }

    bool diag = (kt == ktmax);   // only the diagonal tile needs masking
#pragma unroll
    for (int mi = 0; mi < 2; ++mi)
#pragma unroll
      for (int nj = 0; nj < 2; ++nj)
#pragma unroll
        for (int r = 0; r < 4; ++r) {
          float v = s[mi][nj][r] * 0.125f;
          v = fmaxf(v, 0.f);
          if (diag && (nj * 16 + l16 > mi * 16 + g * 4 + r)) v = 0.f;
          pw[(mi * 16 + g * 4 + r) * 40 + nj * 16 + l16] = f2bf(v);
        }

    bf16x8 pa[2];
#pragma unroll
    for (int mi = 0; mi < 2; ++mi)
      pa[mi] = __builtin_bit_cast(bf16x8,
          *reinterpret_cast<const u16x8*>(pw + (mi * 16 + l16) * 40 + g * 8));
#pragma unroll
    for (int ni = 0; ni < 4; ++ni) {
      bf16x8 vf = __builtin_bit_cast(bf16x8,
          *reinterpret_cast<const u16x8*>(Vt + (ni * 16 + l16) * 1024 + kbase + g * 8));
#pragma unroll
      for (int mi = 0; mi < 2; ++mi)
        y[mi][ni] = __builtin_amdgcn_mfma_f32_16x16x32_bf16(pa[mi], vf, y[mi][ni], 0, 0, 0);
    }
  }

  // out[b, t, h*64+d] f32
  float* outp = out + (size_t)b * 1024 * 768 + (size_t)h * 64;
#pragma unroll
  for (int mi = 0; mi < 2; ++mi)
#pragma unroll
    for (int r = 0; r < 4; ++r) {
      int t = q0 + mi * 16 + g * 4 + r;
#pragma unroll
      for (int ni = 0; ni < 4; ++ni)
        outp[(size_t)t * 768 + ni * 16 + l16] = y[mi][ni][r];
    }
}

extern "C" void kernel_launch(void* const* d_in, const int* in_sizes, int n_in,
                              void* d_out, int out_size, void* d_ws, size_t ws_size,
                              hipStream_t stream) {
  const float* x    = (const float*)d_in[0];
  const float* W    = (const float*)d_in[1];
  const float* bias = (const float*)d_in[2];
  float* out = (float*)d_out;
  char* ws = (char*)d_ws;

  // ws layout (bytes): xb 12.58MB | WbT 3.54MB | qb 12.58MB | kb 12.58MB | vTb 12.58MB
  u16* xb  = (u16*)(ws);
  u16* WbT = (u16*)(ws + 12582912);
  u16* qb  = (u16*)(ws + 16121856);
  u16* kb  = (u16*)(ws + 28704768);
  u16* vTb = (u16*)(ws + 41287680);

  hipLaunchKernelGGL(cvt_x_kernel, dim3(3072), dim3(256), 0, stream, x, xb);
  hipLaunchKernelGGL(cvt_wT_kernel, dim3(9, 192), dim3(256), 0, stream, W, WbT);
  hipLaunchKernelGGL(gemm_qkv_kernel, dim3(64, 18), dim3(256), 0, stream,
                     xb, WbT, bias, qb, kb, vTb);
  hipLaunchKernelGGL(attn_kernel, dim3(96, 8), dim3(256), 0, stream, qb, kb, vTb, out);
}

// Round 2
// 138.566 us; speedup vs baseline: 1.0459x; 1.0459x over previous
//
#include <hip/hip_runtime.h>

typedef unsigned short u16;
typedef u16 u16x4 __attribute__((ext_vector_type(4)));
typedef u16 u16x8 __attribute__((ext_vector_type(8)));
typedef __bf16 bf16x8 __attribute__((ext_vector_type(8)));
typedef float f32x4 __attribute__((ext_vector_type(4)));

static __device__ __forceinline__ u16 f2bf(float f) {
  unsigned u = __builtin_bit_cast(unsigned, f);
  u += 0x7FFFu + ((u >> 16) & 1u);   // RTNE
  return (u16)(u >> 16);
}

// async global->LDS, 16B per lane. LDS dest = wave-uniform base + lane*16.
static __device__ __forceinline__ void gload16(const u16* g, u16* l) {
  __builtin_amdgcn_global_load_lds(
      (const __attribute__((address_space(1))) unsigned*)g,
      (__attribute__((address_space(3))) unsigned*)l, 16, 0, 0);
}

// ---------------- x f32 -> bf16 ----------------
__global__ __launch_bounds__(256) void cvt_x_kernel(const float* __restrict__ in,
                                                    u16* __restrict__ out) {
  int i = blockIdx.x * 256 + threadIdx.x;          // 8 elems per thread
  const float4* p = reinterpret_cast<const float4*>(in) + (size_t)i * 2;
  float4 a = p[0], b = p[1];
  u16x8 o;
  o[0] = f2bf(a.x); o[1] = f2bf(a.y); o[2] = f2bf(a.z); o[3] = f2bf(a.w);
  o[4] = f2bf(b.x); o[5] = f2bf(b.y); o[6] = f2bf(b.z); o[7] = f2bf(b.w);
  reinterpret_cast<u16x8*>(out)[i] = o;
}

// ---------------- W [768][2304] f32 -> WbT [2304][768] bf16 ----------------
__global__ __launch_bounds__(256) void cvt_wT_kernel(const float* __restrict__ W,
                                                     u16* __restrict__ WT) {
  int n  = blockIdx.x * 256 + threadIdx.x;   // 0..2303 (gridDim.x = 9)
  int k0 = blockIdx.y * 4;                   // gridDim.y = 192
  u16x4 o;
#pragma unroll
  for (int j = 0; j < 4; ++j) o[j] = f2bf(W[(size_t)(k0 + j) * 2304 + n]);
  *reinterpret_cast<u16x4*>(WT + (size_t)n * 768 + k0) = o;
}

// ---------------- QKV GEMM: [8192x768] @ [768x2304] + bias ----------------
// m97 structure: linear LDS [128][32], global_load_lds width=16, 2-barrier loop.
// writes q[bh][t][d], k[bh][t][d], vT[bh][d][t]  (all bf16)
__global__ __launch_bounds__(256) void gemm_qkv_kernel(
    const u16* __restrict__ A, const u16* __restrict__ Bt,
    const float* __restrict__ bias,
    u16* __restrict__ qb, u16* __restrict__ kb, u16* __restrict__ vTb) {
  __shared__ __align__(16) u16 as[128 * 32];
  __shared__ __align__(16) u16 bs[128 * 32];
  const int K = 768;
  int tid = threadIdx.x;
  int lane = tid & 63;
  int wave = tid >> 6;
  int m0 = blockIdx.x * 128;       // gridDim.x = 64
  int n0 = blockIdx.y * 128;       // gridDim.y = 18
  int wm = (wave >> 1) * 64;
  int wn = (wave & 1) * 64;
  int l16 = lane & 15, g = lane >> 4;

  // staging: wave w owns tile rows [w*32, w*32+32), 2 instrs of 16 rows each.
  // lane l -> row_local = i*16 + l/4, chunk = l&3 (8 elems), LDS linear [128][32].
  const u16* gA = A  + (size_t)(m0 + wave * 32 + (lane >> 2)) * K + (lane & 3) * 8;
  const u16* gB = Bt + (size_t)(n0 + wave * 32 + (lane >> 2)) * K + (lane & 3) * 8;
  u16* lA = as + wave * 1024;   // elems; +512 for instr 1
  u16* lB = bs + wave * 1024;

  f32x4 acc[4][4];
#pragma unroll
  for (int mi = 0; mi < 4; ++mi)
#pragma unroll
    for (int ni = 0; ni < 4; ++ni) acc[mi][ni] = (f32x4){0.f, 0.f, 0.f, 0.f};

  for (int k0 = 0; k0 < K; k0 += 32) {
    __syncthreads();   // prev iteration's LDS reads done before overwrite
    gload16(gA + k0,            lA);
    gload16(gA + k0 + 16 * K,   lA + 512);
    gload16(gB + k0,            lB);
    gload16(gB + k0 + 16 * K,   lB + 512);
    __syncthreads();   // compiler drains vmcnt(0) before barrier -> staging done

    bf16x8 af[4], bf[4];
#pragma unroll
    for (int mi = 0; mi < 4; ++mi)
      af[mi] = __builtin_bit_cast(bf16x8,
          *reinterpret_cast<const u16x8*>(as + (wm + mi * 16 + l16) * 32 + g * 8));
#pragma unroll
    for (int ni = 0; ni < 4; ++ni)
      bf[ni] = __builtin_bit_cast(bf16x8,
          *reinterpret_cast<const u16x8*>(bs + (wn + ni * 16 + l16) * 32 + g * 8));
#pragma unroll
    for (int mi = 0; mi < 4; ++mi)
#pragma unroll
      for (int ni = 0; ni < 4; ++ni)
        acc[mi][ni] = __builtin_amdgcn_mfma_f32_16x16x32_bf16(af[mi], bf[ni], acc[mi][ni], 0, 0, 0);
  }

  // epilogue: bias + scatter to q/k/vT (bf16)
  int tbase = m0 & 1023;
  int b = m0 >> 10;
  int g4 = g * 4;
#pragma unroll
  for (int ni = 0; ni < 4; ++ni) {
    int n = n0 + wn + ni * 16 + l16;
    float bv = bias[n];
    int region = n / 768;
    int c = n - region * 768;
    int h = c >> 6, d = c & 63;
    int bh = b * 12 + h;
#pragma unroll
    for (int mi = 0; mi < 4; ++mi) {
      int t0 = tbase + wm + mi * 16 + g4;
      if (region == 2) {
        u16x4 pv;
#pragma unroll
        for (int r = 0; r < 4; ++r) pv[r] = f2bf(acc[mi][ni][r] + bv);
        *reinterpret_cast<u16x4*>(vTb + ((size_t)bh * 64 + d) * 1024 + t0) = pv;
      } else {
        u16* dst = (region == 0) ? qb : kb;
#pragma unroll
        for (int r = 0; r < 4; ++r)
          dst[((size_t)bh * 1024 + t0 + r) * 64 + d] = f2bf(acc[mi][ni][r] + bv);
      }
    }
  }
}

// ---------------- causal relu attention ----------------
// y[b,h,q,:] = sum_{k<=q} relu(scale * q.k) * v[k]
// register double-buffered K/V prefetch; heavy q-blocks dispatched first.
__global__ __launch_bounds__(256) void attn_kernel(
    const u16* __restrict__ qb, const u16* __restrict__ kb,
    const u16* __restrict__ vTb, float* __restrict__ out) {
  __shared__ __align__(16) u16 plds[4][32 * 40];
  int lane = threadIdx.x & 63;
  int wave = threadIdx.x >> 6;
  int bh = blockIdx.x;                           // 0..95
  int q0 = (7 - blockIdx.y) * 128 + wave * 32;   // heaviest blocks first
  int b = bh / 12, h = bh - b * 12;
  const u16* Q  = qb  + (size_t)bh * 65536;
  const u16* Kp = kb  + (size_t)bh * 65536;
  const u16* Vt = vTb + (size_t)bh * 65536;
  int l16 = lane & 15, g = lane >> 4;
  u16* pw = &plds[wave][0];

  bf16x8 qf[2][2];
#pragma unroll
  for (int mi = 0; mi < 2; ++mi)
#pragma unroll
    for (int ks = 0; ks < 2; ++ks)
      qf[mi][ks] = __builtin_bit_cast(bf16x8,
          *reinterpret_cast<const u16x8*>(Q + (q0 + mi * 16 + l16) * 64 + ks * 32 + g * 8));

  f32x4 y[2][4];
#pragma unroll
  for (int mi = 0; mi < 2; ++mi)
#pragma unroll
    for (int ni = 0; ni < 4; ++ni) y[mi][ni] = (f32x4){0.f, 0.f, 0.f, 0.f};

  int ktmax = q0 >> 5;

  // current-tile K/V fragments (registers), prefetch tile 0
  u16x8 kc[4], vc[4];
#pragma unroll
  for (int nj = 0; nj < 2; ++nj)
#pragma unroll
    for (int ks = 0; ks < 2; ++ks)
      kc[nj * 2 + ks] = *reinterpret_cast<const u16x8*>(
          Kp + (nj * 16 + l16) * 64 + ks * 32 + g * 8);
#pragma unroll
  for (int ni = 0; ni < 4; ++ni)
    vc[ni] = *reinterpret_cast<const u16x8*>(Vt + (ni * 16 + l16) * 1024 + g * 8);

  for (int kt = 0; kt <= ktmax; ++kt) {
    int kbase = kt << 5;

    // issue next tile's loads first (hide L2 latency under compute)
    u16x8 kn[4], vn[4];
    if (kt < ktmax) {
      int kb2 = kbase + 32;
#pragma unroll
      for (int nj = 0; nj < 2; ++nj)
#pragma unroll
        for (int ks = 0; ks < 2; ++ks)
          kn[nj * 2 + ks] = *reinterpret_cast<const u16x8*>(
              Kp + (kb2 + nj * 16 + l16) * 64 + ks * 32 + g * 8);
#pragma unroll
      for (int ni = 0; ni < 4; ++ni)
        vn[ni] = *reinterpret_cast<const u16x8*>(Vt + (ni * 16 + l16) * 1024 + kb2 + g * 8);
    }

    f32x4 s[2][2];
#pragma unroll
    for (int mi = 0; mi < 2; ++mi)
#pragma unroll
      for (int nj = 0; nj < 2; ++nj) s[mi][nj] = (f32x4){0.f, 0.f, 0.f, 0.f};

#pragma unroll
    for (int ks = 0; ks < 2; ++ks)
#pragma unroll
      for (int nj = 0; nj < 2; ++nj) {
        bf16x8 kf = __builtin_bit_cast(bf16x8, kc[nj * 2 + ks]);
#pragma unroll
        for (int mi = 0; mi < 2; ++mi)
          s[mi][nj] = __builtin_amdgcn_mfma_f32_16x16x32_bf16(qf[mi][ks], kf, s[mi][nj], 0, 0, 0);
      }

    bool diag = (kt == ktmax);   // only the diagonal tile needs masking
#pragma unroll
    for (int mi = 0; mi < 2; ++mi)
#pragma unroll
      for (int nj = 0; nj < 2; ++nj)
#pragma unroll
        for (int r = 0; r < 4; ++r) {
          float v = s[mi][nj][r] * 0.125f;
          v = fmaxf(v, 0.f);
          if (diag && (nj * 16 + l16 > mi * 16 + g * 4 + r)) v = 0.f;
          pw[(mi * 16 + g * 4 + r) * 40 + nj * 16 + l16] = f2bf(v);
        }

    bf16x8 pa[2];
#pragma unroll
    for (int mi = 0; mi < 2; ++mi)
      pa[mi] = __builtin_bit_cast(bf16x8,
          *reinterpret_cast<const u16x8*>(pw + (mi * 16 + l16) * 40 + g * 8));
#pragma unroll
    for (int ni = 0; ni < 4; ++ni) {
      bf16x8 vf = __builtin_bit_cast(bf16x8, vc[ni]);
#pragma unroll
      for (int mi = 0; mi < 2; ++mi)
        y[mi][ni] = __builtin_amdgcn_mfma_f32_16x16x32_bf16(pa[mi], vf, y[mi][ni], 0, 0, 0);
    }

    if (kt < ktmax) {
#pragma unroll
      for (int i = 0; i < 4; ++i) { kc[i] = kn[i]; vc[i] = vn[i]; }
    }
  }

  // out[b, t, h*64+d] f32
  float* outp = out + (size_t)b * 1024 * 768 + (size_t)h * 64;
#pragma unroll
  for (int mi = 0; mi < 2; ++mi)
#pragma unroll
    for (int r = 0; r < 4; ++r) {
      int t = q0 + mi * 16 + g * 4 + r;
#pragma unroll
      for (int ni = 0; ni < 4; ++ni)
        outp[(size_t)t * 768 + ni * 16 + l16] = y[mi][ni][r];
    }
}

extern "C" void kernel_launch(void* const* d_in, const int* in_sizes, int n_in,
                              void* d_out, int out_size, void* d_ws, size_t ws_size,
                              hipStream_t stream) {
  const float* x    = (const float*)d_in[0];
  const float* W    = (const float*)d_in[1];
  const float* bias = (const float*)d_in[2];
  float* out = (float*)d_out;
  char* ws = (char*)d_ws;

  // ws layout (bytes): xb 12.58MB | WbT 3.54MB | qb 12.58MB | kb 12.58MB | vTb 12.58MB
  u16* xb  = (u16*)(ws);
  u16* WbT = (u16*)(ws + 12582912);
  u16* qb  = (u16*)(ws + 16121856);
  u16* kb  = (u16*)(ws + 28704768);
  u16* vTb = (u16*)(ws + 41287680);

  hipLaunchKernelGGL(cvt_x_kernel, dim3(3072), dim3(256), 0, stream, x, xb);
  hipLaunchKernelGGL(cvt_wT_kernel, dim3(9, 192), dim3(256), 0, stream, W, WbT);
  hipLaunchKernelGGL(gemm_qkv_kernel, dim3(64, 18), dim3(256), 0, stream,
                     xb, WbT, bias, qb, kb, vTb);
  hipLaunchKernelGGL(attn_kernel, dim3(96, 8), dim3(256), 0, stream, qb, kb, vTb, out);
}

// Round 3
// 134.959 us; speedup vs baseline: 1.0738x; 1.0267x over previous
//
#include <hip/hip_runtime.h>
#include <hip/hip_bf16.h>

typedef unsigned short u16;
typedef u16 u16x4 __attribute__((ext_vector_type(4)));
typedef u16 u16x8 __attribute__((ext_vector_type(8)));
typedef __bf16 bf16x8 __attribute__((ext_vector_type(8)));
typedef float f32x4 __attribute__((ext_vector_type(4)));

static __device__ __forceinline__ u16 f2bf(float f) {
  return __builtin_bit_cast(u16, __float2bfloat16(f));   // RTNE, compiler may pair into v_cvt_pk_bf16_f32
}

// async global->LDS, 16B per lane. LDS dest = wave-uniform base + lane*16.
static __device__ __forceinline__ void gload16(const u16* g, u16* l) {
  __builtin_amdgcn_global_load_lds(
      (const __attribute__((address_space(1))) unsigned*)g,
      (__attribute__((address_space(3))) unsigned*)l, 16, 0, 0);
}

// ---------------- x f32 -> bf16 ----------------
__global__ __launch_bounds__(256) void cvt_x_kernel(const float* __restrict__ in,
                                                    u16* __restrict__ out) {
  int i = blockIdx.x * 256 + threadIdx.x;          // 8 elems per thread
  const float4* p = reinterpret_cast<const float4*>(in) + (size_t)i * 2;
  float4 a = p[0], b = p[1];
  u16x8 o;
  o[0] = f2bf(a.x); o[1] = f2bf(a.y); o[2] = f2bf(a.z); o[3] = f2bf(a.w);
  o[4] = f2bf(b.x); o[5] = f2bf(b.y); o[6] = f2bf(b.z); o[7] = f2bf(b.w);
  reinterpret_cast<u16x8*>(out)[i] = o;
}

// ---------------- W [768][2304] f32 -> WbT [2304][768] bf16 ----------------
__global__ __launch_bounds__(256) void cvt_wT_kernel(const float* __restrict__ W,
                                                     u16* __restrict__ WT) {
  int n  = blockIdx.x * 256 + threadIdx.x;   // 0..2303 (gridDim.x = 9)
  int k0 = blockIdx.y * 4;                   // gridDim.y = 192
  u16x4 o;
#pragma unroll
  for (int j = 0; j < 4; ++j) o[j] = f2bf(W[(size_t)(k0 + j) * 2304 + n]);
  *reinterpret_cast<u16x4*>(WT + (size_t)n * 768 + k0) = o;
}

// ---------------- QKV GEMM: [8192x768] @ [768x2304] + bias ----------------
// 2-phase double-buffered LDS, stage-early, global_load_lds width=16.
// writes q[bh][t][d], k[bh][t][d], vT[bh][d][t]  (all bf16)

static __device__ __forceinline__ void gemm_compute(
    const u16* __restrict__ as, const u16* __restrict__ bs,
    int wm, int wn, int l16, int g, f32x4 (&acc)[4][4]) {
  bf16x8 af[4], bfr[4];
#pragma unroll
  for (int mi = 0; mi < 4; ++mi)
    af[mi] = __builtin_bit_cast(bf16x8,
        *reinterpret_cast<const u16x8*>(as + (wm + mi * 16 + l16) * 32 + g * 8));
#pragma unroll
  for (int ni = 0; ni < 4; ++ni)
    bfr[ni] = __builtin_bit_cast(bf16x8,
        *reinterpret_cast<const u16x8*>(bs + (wn + ni * 16 + l16) * 32 + g * 8));
#pragma unroll
  for (int mi = 0; mi < 4; ++mi)
#pragma unroll
    for (int ni = 0; ni < 4; ++ni)
      acc[mi][ni] = __builtin_amdgcn_mfma_f32_16x16x32_bf16(af[mi], bfr[ni], acc[mi][ni], 0, 0, 0);
}

__global__ __launch_bounds__(256) void gemm_qkv_kernel(
    const u16* __restrict__ A, const u16* __restrict__ Bt,
    const float* __restrict__ bias,
    u16* __restrict__ qb, u16* __restrict__ kb, u16* __restrict__ vTb) {
  __shared__ __align__(16) u16 as0[128 * 32], as1[128 * 32];
  __shared__ __align__(16) u16 bs0[128 * 32], bs1[128 * 32];
  const int K = 768;
  int tid = threadIdx.x;
  int lane = tid & 63;
  int wave = tid >> 6;

  // bijective XCD-chunked swizzle: nwg = 64*18 = 1152, 1152/8 = 144 per XCD
  int orig = blockIdx.x + blockIdx.y * 64;
  int wg = (orig & 7) * 144 + (orig >> 3);
  int m0 = (wg & 63) * 128;        // 64 m-blocks
  int n0 = (wg >> 6) * 128;        // 18 n-blocks

  int wm = (wave >> 1) * 64;
  int wn = (wave & 1) * 64;
  int l16 = lane & 15, g = lane >> 4;

  // staging: wave w owns tile rows [w*32, w*32+32), 2 instrs of 16 rows each.
  const u16* gA = A  + (size_t)(m0 + wave * 32 + (lane >> 2)) * K + (lane & 3) * 8;
  const u16* gB = Bt + (size_t)(n0 + wave * 32 + (lane >> 2)) * K + (lane & 3) * 8;
  int lofs = wave * 1024;   // elems; +512 for second 16 rows

  f32x4 acc[4][4];
#pragma unroll
  for (int mi = 0; mi < 4; ++mi)
#pragma unroll
    for (int ni = 0; ni < 4; ++ni) acc[mi][ni] = (f32x4){0.f, 0.f, 0.f, 0.f};

#define STAGE(Abuf, Bbuf, kk)                          \
  do {                                                 \
    gload16(gA + (kk),          Abuf + lofs);          \
    gload16(gA + (kk) + 16 * K, Abuf + lofs + 512);    \
    gload16(gB + (kk),          Bbuf + lofs);          \
    gload16(gB + (kk) + 16 * K, Bbuf + lofs + 512);    \
  } while (0)

  STAGE(as0, bs0, 0);
  __syncthreads();                      // drains prologue stage
  for (int k0 = 0; k0 < K; k0 += 64) {
    if (k0 + 32 < K) STAGE(as1, bs1, k0 + 32);     // issue early
    gemm_compute(as0, bs0, wm, wn, l16, g, acc);   // overlap with in-flight stage
    __syncthreads();                               // drains stage(k0+32)
    if (k0 + 64 < K) STAGE(as0, bs0, k0 + 64);
    gemm_compute(as1, bs1, wm, wn, l16, g, acc);
    __syncthreads();
  }
#undef STAGE

  // epilogue: bias + scatter to q/k/vT (bf16)
  int tbase = m0 & 1023;
  int b = m0 >> 10;
  int g4 = g * 4;
#pragma unroll
  for (int ni = 0; ni < 4; ++ni) {
    int n = n0 + wn + ni * 16 + l16;
    float bv = bias[n];
    int region = n / 768;
    int c = n - region * 768;
    int h = c >> 6, d = c & 63;
    int bh = b * 12 + h;
#pragma unroll
    for (int mi = 0; mi < 4; ++mi) {
      int t0 = tbase + wm + mi * 16 + g4;
      if (region == 2) {
        u16x4 pv;
#pragma unroll
        for (int r = 0; r < 4; ++r) pv[r] = f2bf(acc[mi][ni][r] + bv);
        *reinterpret_cast<u16x4*>(vTb + ((size_t)bh * 64 + d) * 1024 + t0) = pv;
      } else {
        u16* dst = (region == 0) ? qb : kb;
#pragma unroll
        for (int r = 0; r < 4; ++r)
          dst[((size_t)bh * 1024 + t0 + r) * 64 + d] = f2bf(acc[mi][ni][r] + bv);
      }
    }
  }
}

// ---------------- causal relu attention ----------------
// y[b,h,q,:] = sum_{k<=q} relu(scale * q.k) * v[k]
// register double-buffered K/V prefetch; heavy q-blocks dispatched first.
__global__ __launch_bounds__(256) void attn_kernel(
    const u16* __restrict__ qb, const u16* __restrict__ kb,
    const u16* __restrict__ vTb, float* __restrict__ out) {
  __shared__ __align__(16) u16 plds[4][32 * 40];
  int lane = threadIdx.x & 63;
  int wave = threadIdx.x >> 6;
  int bh = blockIdx.x;                           // 0..95
  int q0 = (7 - blockIdx.y) * 128 + wave * 32;   // heaviest blocks first
  int b = bh / 12, h = bh - b * 12;
  const u16* Q  = qb  + (size_t)bh * 65536;
  const u16* Kp = kb  + (size_t)bh * 65536;
  const u16* Vt = vTb + (size_t)bh * 65536;
  int l16 = lane & 15, g = lane >> 4;
  u16* pw = &plds[wave][0];

  bf16x8 qf[2][2];
#pragma unroll
  for (int mi = 0; mi < 2; ++mi)
#pragma unroll
    for (int ks = 0; ks < 2; ++ks)
      qf[mi][ks] = __builtin_bit_cast(bf16x8,
          *reinterpret_cast<const u16x8*>(Q + (q0 + mi * 16 + l16) * 64 + ks * 32 + g * 8));

  f32x4 y[2][4];
#pragma unroll
  for (int mi = 0; mi < 2; ++mi)
#pragma unroll
    for (int ni = 0; ni < 4; ++ni) y[mi][ni] = (f32x4){0.f, 0.f, 0.f, 0.f};

  int ktmax = q0 >> 5;

  // current-tile K/V fragments (registers), prefetch tile 0
  u16x8 kc[4], vc[4];
#pragma unroll
  for (int nj = 0; nj < 2; ++nj)
#pragma unroll
    for (int ks = 0; ks < 2; ++ks)
      kc[nj * 2 + ks] = *reinterpret_cast<const u16x8*>(
          Kp + (nj * 16 + l16) * 64 + ks * 32 + g * 8);
#pragma unroll
  for (int ni = 0; ni < 4; ++ni)
    vc[ni] = *reinterpret_cast<const u16x8*>(Vt + (ni * 16 + l16) * 1024 + g * 8);

  for (int kt = 0; kt <= ktmax; ++kt) {
    int kbase = kt << 5;

    // issue next tile's loads first (hide L2 latency under compute)
    u16x8 kn[4], vn[4];
    if (kt < ktmax) {
      int kb2 = kbase + 32;
#pragma unroll
      for (int nj = 0; nj < 2; ++nj)
#pragma unroll
        for (int ks = 0; ks < 2; ++ks)
          kn[nj * 2 + ks] = *reinterpret_cast<const u16x8*>(
              Kp + (kb2 + nj * 16 + l16) * 64 + ks * 32 + g * 8);
#pragma unroll
      for (int ni = 0; ni < 4; ++ni)
        vn[ni] = *reinterpret_cast<const u16x8*>(Vt + (ni * 16 + l16) * 1024 + kb2 + g * 8);
    }

    f32x4 s[2][2];
#pragma unroll
    for (int mi = 0; mi < 2; ++mi)
#pragma unroll
      for (int nj = 0; nj < 2; ++nj) s[mi][nj] = (f32x4){0.f, 0.f, 0.f, 0.f};

#pragma unroll
    for (int ks = 0; ks < 2; ++ks)
#pragma unroll
      for (int nj = 0; nj < 2; ++nj) {
        bf16x8 kf = __builtin_bit_cast(bf16x8, kc[nj * 2 + ks]);
#pragma unroll
        for (int mi = 0; mi < 2; ++mi)
          s[mi][nj] = __builtin_amdgcn_mfma_f32_16x16x32_bf16(qf[mi][ks], kf, s[mi][nj], 0, 0, 0);
      }

    bool diag = (kt == ktmax);   // only the diagonal tile needs masking
#pragma unroll
    for (int mi = 0; mi < 2; ++mi)
#pragma unroll
      for (int nj = 0; nj < 2; ++nj)
#pragma unroll
        for (int r = 0; r < 4; ++r) {
          float v = s[mi][nj][r] * 0.125f;
          v = fmaxf(v, 0.f);
          if (diag && (nj * 16 + l16 > mi * 16 + g * 4 + r)) v = 0.f;
          pw[(mi * 16 + g * 4 + r) * 40 + nj * 16 + l16] = f2bf(v);
        }

    bf16x8 pa[2];
#pragma unroll
    for (int mi = 0; mi < 2; ++mi)
      pa[mi] = __builtin_bit_cast(bf16x8,
          *reinterpret_cast<const u16x8*>(pw + (mi * 16 + l16) * 40 + g * 8));
#pragma unroll
    for (int ni = 0; ni < 4; ++ni) {
      bf16x8 vf = __builtin_bit_cast(bf16x8, vc[ni]);
#pragma unroll
      for (int mi = 0; mi < 2; ++mi)
        y[mi][ni] = __builtin_amdgcn_mfma_f32_16x16x32_bf16(pa[mi], vf, y[mi][ni], 0, 0, 0);
    }

    if (kt < ktmax) {
#pragma unroll
      for (int i = 0; i < 4; ++i) { kc[i] = kn[i]; vc[i] = vn[i]; }
    }
  }

  // out[b, t, h*64+d] f32
  float* outp = out + (size_t)b * 1024 * 768 + (size_t)h * 64;
#pragma unroll
  for (int mi = 0; mi < 2; ++mi)
#pragma unroll
    for (int r = 0; r < 4; ++r) {
      int t = q0 + mi * 16 + g * 4 + r;
#pragma unroll
      for (int ni = 0; ni < 4; ++ni)
        outp[(size_t)t * 768 + ni * 16 + l16] = y[mi][ni][r];
    }
}

extern "C" void kernel_launch(void* const* d_in, const int* in_sizes, int n_in,
                              void* d_out, int out_size, void* d_ws, size_t ws_size,
                              hipStream_t stream) {
  const float* x    = (const float*)d_in[0];
  const float* W    = (const float*)d_in[1];
  const float* bias = (const float*)d_in[2];
  float* out = (float*)d_out;
  char* ws = (char*)d_ws;

  // ws layout (bytes): xb 12.58MB | WbT 3.54MB | qb 12.58MB | kb 12.58MB | vTb 12.58MB
  u16* xb  = (u16*)(ws);
  u16* WbT = (u16*)(ws + 12582912);
  u16* qb  = (u16*)(ws + 16121856);
  u16* kb  = (u16*)(ws + 28704768);
  u16* vTb = (u16*)(ws + 41287680);

  hipLaunchKernelGGL(cvt_x_kernel, dim3(3072), dim3(256), 0, stream, x, xb);
  hipLaunchKernelGGL(cvt_wT_kernel, dim3(9, 192), dim3(256), 0, stream, W, WbT);
  hipLaunchKernelGGL(gemm_qkv_kernel, dim3(64, 18), dim3(256), 0, stream,
                     xb, WbT, bias, qb, kb, vTb);
  hipLaunchKernelGGL(attn_kernel, dim3(96, 8), dim3(256), 0, stream, qb, kb, vTb, out);
}

// Round 4
// 129.447 us; speedup vs baseline: 1.1195x; 1.0426x over previous
//
#include <hip/hip_runtime.h>
#include <hip/hip_bf16.h>

typedef unsigned short u16;
typedef u16 u16x4 __attribute__((ext_vector_type(4)));
typedef u16 u16x8 __attribute__((ext_vector_type(8)));
typedef __bf16 bf16x8 __attribute__((ext_vector_type(8)));
typedef float f32x4 __attribute__((ext_vector_type(4)));

static __device__ __forceinline__ u16 f2bf(float f) {
  unsigned u = __builtin_bit_cast(unsigned, f);
  u += 0x7FFFu + ((u >> 16) & 1u);   // RTNE
  return (u16)(u >> 16);
}

// async global->LDS, 16B per lane. LDS dest = wave-uniform base + lane*16.
static __device__ __forceinline__ void gload16(const u16* g, u16* l) {
  __builtin_amdgcn_global_load_lds(
      (const __attribute__((address_space(1))) unsigned*)g,
      (__attribute__((address_space(3))) unsigned*)l, 16, 0, 0);
}

// ---------------- x f32 -> bf16 ----------------
__global__ __launch_bounds__(256) void cvt_x_kernel(const float* __restrict__ in,
                                                    u16* __restrict__ out) {
  int i = blockIdx.x * 256 + threadIdx.x;          // 8 elems per thread
  const float4* p = reinterpret_cast<const float4*>(in) + (size_t)i * 2;
  float4 a = p[0], b = p[1];
  u16x8 o;
  o[0] = f2bf(a.x); o[1] = f2bf(a.y); o[2] = f2bf(a.z); o[3] = f2bf(a.w);
  o[4] = f2bf(b.x); o[5] = f2bf(b.y); o[6] = f2bf(b.z); o[7] = f2bf(b.w);
  reinterpret_cast<u16x8*>(out)[i] = o;
}

// ---------------- W [768][2304] f32 -> WbT [2304][768] bf16 ----------------
__global__ __launch_bounds__(256) void cvt_wT_kernel(const float* __restrict__ W,
                                                     u16* __restrict__ WT) {
  int n  = blockIdx.x * 256 + threadIdx.x;   // 0..2303 (gridDim.x = 9)
  int k0 = blockIdx.y * 4;                   // gridDim.y = 192
  u16x4 o;
#pragma unroll
  for (int j = 0; j < 4; ++j) o[j] = f2bf(W[(size_t)(k0 + j) * 2304 + n]);
  *reinterpret_cast<u16x4*>(WT + (size_t)n * 768 + k0) = o;
}

// ---------------- QKV GEMM: [8192x768] @ [768x2304] + bias ----------------
// 2-phase double-buffered LDS, stage-early, global_load_lds width=16.
// Default block mapping: m%8 == XCD -> per-XCD footprint = 1.6MB A + 3.5MB B (L2-fit).
// writes q[bh][t][d], k[bh][t][d], vT[bh][d][t]  (all bf16)

static __device__ __forceinline__ void gemm_compute(
    const u16* __restrict__ as, const u16* __restrict__ bs,
    int wm, int wn, int l16, int g, f32x4 (&acc)[4][4]) {
  bf16x8 af[4], bfr[4];
#pragma unroll
  for (int mi = 0; mi < 4; ++mi)
    af[mi] = __builtin_bit_cast(bf16x8,
        *reinterpret_cast<const u16x8*>(as + (wm + mi * 16 + l16) * 32 + g * 8));
#pragma unroll
  for (int ni = 0; ni < 4; ++ni)
    bfr[ni] = __builtin_bit_cast(bf16x8,
        *reinterpret_cast<const u16x8*>(bs + (wn + ni * 16 + l16) * 32 + g * 8));
#pragma unroll
  for (int mi = 0; mi < 4; ++mi)
#pragma unroll
    for (int ni = 0; ni < 4; ++ni)
      acc[mi][ni] = __builtin_amdgcn_mfma_f32_16x16x32_bf16(af[mi], bfr[ni], acc[mi][ni], 0, 0, 0);
}

__global__ __launch_bounds__(256, 3) void gemm_qkv_kernel(
    const u16* __restrict__ A, const u16* __restrict__ Bt,
    const float* __restrict__ bias,
    u16* __restrict__ qb, u16* __restrict__ kb, u16* __restrict__ vTb) {
  __shared__ __align__(16) u16 as0[128 * 32], as1[128 * 32];
  __shared__ __align__(16) u16 bs0[128 * 32], bs1[128 * 32];
  const int K = 768;
  int tid = threadIdx.x;
  int lane = tid & 63;
  int wave = tid >> 6;

  int m0 = blockIdx.x * 128;       // gridDim.x = 64 (64%8==0 -> natural XCD locality)
  int n0 = blockIdx.y * 128;       // gridDim.y = 18

  int wm = (wave >> 1) * 64;
  int wn = (wave & 1) * 64;
  int l16 = lane & 15, g = lane >> 4;

  // staging: wave w owns tile rows [w*32, w*32+32), 2 instrs of 16 rows each.
  const u16* gA = A  + (size_t)(m0 + wave * 32 + (lane >> 2)) * K + (lane & 3) * 8;
  const u16* gB = Bt + (size_t)(n0 + wave * 32 + (lane >> 2)) * K + (lane & 3) * 8;
  int lofs = wave * 1024;   // elems; +512 for second 16 rows

  f32x4 acc[4][4];
#pragma unroll
  for (int mi = 0; mi < 4; ++mi)
#pragma unroll
    for (int ni = 0; ni < 4; ++ni) acc[mi][ni] = (f32x4){0.f, 0.f, 0.f, 0.f};

#define STAGE(Abuf, Bbuf, kk)                          \
  do {                                                 \
    gload16(gA + (kk),          Abuf + lofs);          \
    gload16(gA + (kk) + 16 * K, Abuf + lofs + 512);    \
    gload16(gB + (kk),          Bbuf + lofs);          \
    gload16(gB + (kk) + 16 * K, Bbuf + lofs + 512);    \
  } while (0)

  STAGE(as0, bs0, 0);
  __syncthreads();                      // drains prologue stage
  for (int k0 = 0; k0 < K; k0 += 64) {
    if (k0 + 32 < K) STAGE(as1, bs1, k0 + 32);     // issue early
    gemm_compute(as0, bs0, wm, wn, l16, g, acc);   // overlap with in-flight stage
    __syncthreads();                               // drains stage(k0+32)
    if (k0 + 64 < K) STAGE(as0, bs0, k0 + 64);
    gemm_compute(as1, bs1, wm, wn, l16, g, acc);
    __syncthreads();
  }
#undef STAGE

  // epilogue: bias + scatter to q/k/vT (bf16)
  int tbase = m0 & 1023;
  int b = m0 >> 10;
  int g4 = g * 4;
#pragma unroll
  for (int ni = 0; ni < 4; ++ni) {
    int n = n0 + wn + ni * 16 + l16;
    float bv = bias[n];
    int region = n / 768;
    int c = n - region * 768;
    int h = c >> 6, d = c & 63;
    int bh = b * 12 + h;
#pragma unroll
    for (int mi = 0; mi < 4; ++mi) {
      int t0 = tbase + wm + mi * 16 + g4;
      if (region == 2) {
        u16x4 pv;
#pragma unroll
        for (int r = 0; r < 4; ++r) pv[r] = f2bf(acc[mi][ni][r] + bv);
        *reinterpret_cast<u16x4*>(vTb + ((size_t)bh * 64 + d) * 1024 + t0) = pv;
      } else {
        u16* dst = (region == 0) ? qb : kb;
#pragma unroll
        for (int r = 0; r < 4; ++r)
          dst[((size_t)bh * 1024 + t0 + r) * 64 + d] = f2bf(acc[mi][ni][r] + bv);
      }
    }
  }
}

// ---------------- causal relu attention ----------------
// y[b,h,q,:] = sum_{k<=q} relu(scale * q.k) * v[k]
// swapped QK^T (A=K, B=Q) -> P rows packed per-lane -> ds_write_b64 x4/tile.
__global__ __launch_bounds__(256) void attn_kernel(
    const u16* __restrict__ qb, const u16* __restrict__ kb,
    const u16* __restrict__ vTb, float* __restrict__ out) {
  __shared__ __align__(16) u16 plds[4][32 * 40];
  int lane = threadIdx.x & 63;
  int wave = threadIdx.x >> 6;
  int bh = blockIdx.x;                           // 0..95
  int q0 = (7 - blockIdx.y) * 128 + wave * 32;   // heaviest blocks first
  int b = bh / 12, h = bh - b * 12;
  const u16* Q  = qb  + (size_t)bh * 65536;
  const u16* Kp = kb  + (size_t)bh * 65536;
  const u16* Vt = vTb + (size_t)bh * 65536;
  int l16 = lane & 15, g = lane >> 4;
  u16* pw = &plds[wave][0];

  bf16x8 qf[2][2];
#pragma unroll
  for (int mi = 0; mi < 2; ++mi)
#pragma unroll
    for (int ks = 0; ks < 2; ++ks)
      qf[mi][ks] = __builtin_bit_cast(bf16x8,
          *reinterpret_cast<const u16x8*>(Q + (q0 + mi * 16 + l16) * 64 + ks * 32 + g * 8));

  f32x4 y[2][4];
#pragma unroll
  for (int mi = 0; mi < 2; ++mi)
#pragma unroll
    for (int ni = 0; ni < 4; ++ni) y[mi][ni] = (f32x4){0.f, 0.f, 0.f, 0.f};

  int ktmax = q0 >> 5;

  // current-tile K/V fragments (registers), prefetch tile 0
  u16x8 kc[4], vc[4];
#pragma unroll
  for (int nj = 0; nj < 2; ++nj)
#pragma unroll
    for (int ks = 0; ks < 2; ++ks)
      kc[nj * 2 + ks] = *reinterpret_cast<const u16x8*>(
          Kp + (nj * 16 + l16) * 64 + ks * 32 + g * 8);
#pragma unroll
  for (int ni = 0; ni < 4; ++ni)
    vc[ni] = *reinterpret_cast<const u16x8*>(Vt + (ni * 16 + l16) * 1024 + g * 8);

  for (int kt = 0; kt <= ktmax; ++kt) {
    int kbase = kt << 5;

    // issue next tile's loads first (hide L2 latency under compute)
    u16x8 kn[4], vn[4];
    if (kt < ktmax) {
      int kb2 = kbase + 32;
#pragma unroll
      for (int nj = 0; nj < 2; ++nj)
#pragma unroll
        for (int ks = 0; ks < 2; ++ks)
          kn[nj * 2 + ks] = *reinterpret_cast<const u16x8*>(
              Kp + (kb2 + nj * 16 + l16) * 64 + ks * 32 + g * 8);
#pragma unroll
      for (int ni = 0; ni < 4; ++ni)
        vn[ni] = *reinterpret_cast<const u16x8*>(Vt + (ni * 16 + l16) * 1024 + kb2 + g * 8);
    }

    // S^T compute: s2[kj][qi] = mfma(A=K_rows, B=Q_rows)
    // D lane layout: q = qi*16 + l16 (col), key = kj*16 + g*4 + r (row)
    f32x4 s2[2][2];
#pragma unroll
    for (int kj = 0; kj < 2; ++kj)
#pragma unroll
      for (int qi = 0; qi < 2; ++qi) s2[kj][qi] = (f32x4){0.f, 0.f, 0.f, 0.f};

#pragma unroll
    for (int ks = 0; ks < 2; ++ks)
#pragma unroll
      for (int kj = 0; kj < 2; ++kj) {
        bf16x8 kf = __builtin_bit_cast(bf16x8, kc[kj * 2 + ks]);
#pragma unroll
        for (int qi = 0; qi < 2; ++qi)
          s2[kj][qi] = __builtin_amdgcn_mfma_f32_16x16x32_bf16(kf, qf[qi][ks], s2[kj][qi], 0, 0, 0);
      }

    bool diag = (kt == ktmax);   // only the diagonal tile needs masking
#pragma unroll
    for (int kj = 0; kj < 2; ++kj)
#pragma unroll
      for (int qi = 0; qi < 2; ++qi) {
        u16x4 pv;
#pragma unroll
        for (int r = 0; r < 4; ++r) {
          float v = s2[kj][qi][r] * 0.125f;
          v = fmaxf(v, 0.f);
          if (diag && (kj * 16 + g * 4 + r > qi * 16 + l16)) v = 0.f;
          pv[r] = f2bf(v);
        }
        // P[q][key]: 4 consecutive keys per lane -> one b64 store
        *reinterpret_cast<u16x4*>(pw + (qi * 16 + l16) * 40 + kj * 16 + g * 4) = pv;
      }

    bf16x8 pa[2];
#pragma unroll
    for (int mi = 0; mi < 2; ++mi)
      pa[mi] = __builtin_bit_cast(bf16x8,
          *reinterpret_cast<const u16x8*>(pw + (mi * 16 + l16) * 40 + g * 8));
#pragma unroll
    for (int ni = 0; ni < 4; ++ni) {
      bf16x8 vf = __builtin_bit_cast(bf16x8, vc[ni]);
#pragma unroll
      for (int mi = 0; mi < 2; ++mi)
        y[mi][ni] = __builtin_amdgcn_mfma_f32_16x16x32_bf16(pa[mi], vf, y[mi][ni], 0, 0, 0);
    }

    if (kt < ktmax) {
#pragma unroll
      for (int i = 0; i < 4; ++i) { kc[i] = kn[i]; vc[i] = vn[i]; }
    }
  }

  // out[b, t, h*64+d] f32
  float* outp = out + (size_t)b * 1024 * 768 + (size_t)h * 64;
#pragma unroll
  for (int mi = 0; mi < 2; ++mi)
#pragma unroll
    for (int r = 0; r < 4; ++r) {
      int t = q0 + mi * 16 + g * 4 + r;
#pragma unroll
      for (int ni = 0; ni < 4; ++ni)
        outp[(size_t)t * 768 + ni * 16 + l16] = y[mi][ni][r];
    }
}

extern "C" void kernel_launch(void* const* d_in, const int* in_sizes, int n_in,
                              void* d_out, int out_size, void* d_ws, size_t ws_size,
                              hipStream_t stream) {
  const float* x    = (const float*)d_in[0];
  const float* W    = (const float*)d_in[1];
  const float* bias = (const float*)d_in[2];
  float* out = (float*)d_out;
  char* ws = (char*)d_ws;

  // ws layout (bytes): xb 12.58MB | WbT 3.54MB | qb 12.58MB | kb 12.58MB | vTb 12.58MB
  u16* xb  = (u16*)(ws);
  u16* WbT = (u16*)(ws + 12582912);
  u16* qb  = (u16*)(ws + 16121856);
  u16* kb  = (u16*)(ws + 28704768);
  u16* vTb = (u16*)(ws + 41287680);

  hipLaunchKernelGGL(cvt_x_kernel, dim3(3072), dim3(256), 0, stream, x, xb);
  hipLaunchKernelGGL(cvt_wT_kernel, dim3(9, 192), dim3(256), 0, stream, W, WbT);
  hipLaunchKernelGGL(gemm_qkv_kernel, dim3(64, 18), dim3(256), 0, stream,
                     xb, WbT, bias, qb, kb, vTb);
  hipLaunchKernelGGL(attn_kernel, dim3(96, 8), dim3(256), 0, stream, qb, kb, vTb, out);
}

// Round 5
// 120.020 us; speedup vs baseline: 1.2075x; 1.0786x over previous
//
#include <hip/hip_runtime.h>
#include <hip/hip_bf16.h>

typedef unsigned short u16;
typedef u16 u16x4 __attribute__((ext_vector_type(4)));
typedef u16 u16x8 __attribute__((ext_vector_type(8)));
typedef __bf16 bf16x8 __attribute__((ext_vector_type(8)));
typedef float f32x4 __attribute__((ext_vector_type(4)));

static __device__ __forceinline__ u16 f2bf(float f) {
  return __builtin_bit_cast(u16, __float2bfloat16(f));   // RTNE; compiler pairs into v_cvt_pk_bf16_f32
}

// async global->LDS, 16B per lane. LDS dest = wave-uniform base + lane*16.
static __device__ __forceinline__ void gload16(const u16* g, u16* l) {
  __builtin_amdgcn_global_load_lds(
      (const __attribute__((address_space(1))) unsigned*)g,
      (__attribute__((address_space(3))) unsigned*)l, 16, 0, 0);
}

// ---------------- x f32 -> bf16 ----------------
__global__ __launch_bounds__(256) void cvt_x_kernel(const float* __restrict__ in,
                                                    u16* __restrict__ out) {
  int i = blockIdx.x * 256 + threadIdx.x;          // 8 elems per thread
  const float4* p = reinterpret_cast<const float4*>(in) + (size_t)i * 2;
  float4 a = p[0], b = p[1];
  u16x8 o;
  o[0] = f2bf(a.x); o[1] = f2bf(a.y); o[2] = f2bf(a.z); o[3] = f2bf(a.w);
  o[4] = f2bf(b.x); o[5] = f2bf(b.y); o[6] = f2bf(b.z); o[7] = f2bf(b.w);
  reinterpret_cast<u16x8*>(out)[i] = o;
}

// ---------------- W [768][2304] f32 -> WbT [2304][768] bf16 ----------------
__global__ __launch_bounds__(256) void cvt_wT_kernel(const float* __restrict__ W,
                                                     u16* __restrict__ WT) {
  int n  = blockIdx.x * 256 + threadIdx.x;   // 0..2303 (gridDim.x = 9)
  int k0 = blockIdx.y * 4;                   // gridDim.y = 192
  u16x4 o;
#pragma unroll
  for (int j = 0; j < 4; ++j) o[j] = f2bf(W[(size_t)(k0 + j) * 2304 + n]);
  *reinterpret_cast<u16x4*>(WT + (size_t)n * 768 + k0) = o;
}

// ---------------- QKV GEMM: [8192x768] @ [768x2304] + bias ----------------
// 2-phase double-buffered LDS, stage-early, global_load_lds width=16, 4 blocks/CU.
// writes q[bh][t][d], k[bh][t][d], vT[bh][d][t]  (all bf16)

static __device__ __forceinline__ void gemm_compute(
    const u16* __restrict__ as, const u16* __restrict__ bs,
    int wm, int wn, int l16, int g, f32x4 (&acc)[4][4]) {
  bf16x8 af[4], bfr[4];
#pragma unroll
  for (int mi = 0; mi < 4; ++mi)
    af[mi] = __builtin_bit_cast(bf16x8,
        *reinterpret_cast<const u16x8*>(as + (wm + mi * 16 + l16) * 32 + g * 8));
#pragma unroll
  for (int ni = 0; ni < 4; ++ni)
    bfr[ni] = __builtin_bit_cast(bf16x8,
        *reinterpret_cast<const u16x8*>(bs + (wn + ni * 16 + l16) * 32 + g * 8));
#pragma unroll
  for (int mi = 0; mi < 4; ++mi)
#pragma unroll
    for (int ni = 0; ni < 4; ++ni)
      acc[mi][ni] = __builtin_amdgcn_mfma_f32_16x16x32_bf16(af[mi], bfr[ni], acc[mi][ni], 0, 0, 0);
}

__global__ __launch_bounds__(256, 4) void gemm_qkv_kernel(
    const u16* __restrict__ A, const u16* __restrict__ Bt,
    const float* __restrict__ bias,
    u16* __restrict__ qb, u16* __restrict__ kb, u16* __restrict__ vTb) {
  __shared__ __align__(16) u16 as0[128 * 32], as1[128 * 32];
  __shared__ __align__(16) u16 bs0[128 * 32], bs1[128 * 32];
  const int K = 768;
  int tid = threadIdx.x;
  int lane = tid & 63;
  int wave = tid >> 6;

  int m0 = blockIdx.x * 128;       // gridDim.x = 64 (m%8==XCD -> per-XCD L2-fit footprint)
  int n0 = blockIdx.y * 128;       // gridDim.y = 18

  int wm = (wave >> 1) * 64;
  int wn = (wave & 1) * 64;
  int l16 = lane & 15, g = lane >> 4;

  // staging: wave w owns tile rows [w*32, w*32+32), 2 instrs of 16 rows each.
  const u16* gA = A  + (size_t)(m0 + wave * 32 + (lane >> 2)) * K + (lane & 3) * 8;
  const u16* gB = Bt + (size_t)(n0 + wave * 32 + (lane >> 2)) * K + (lane & 3) * 8;
  int lofs = wave * 1024;   // elems; +512 for second 16 rows

  f32x4 acc[4][4];
#pragma unroll
  for (int mi = 0; mi < 4; ++mi)
#pragma unroll
    for (int ni = 0; ni < 4; ++ni) acc[mi][ni] = (f32x4){0.f, 0.f, 0.f, 0.f};

#define STAGE(Abuf, Bbuf, kk)                          \
  do {                                                 \
    gload16(gA + (kk),          Abuf + lofs);          \
    gload16(gA + (kk) + 16 * K, Abuf + lofs + 512);    \
    gload16(gB + (kk),          Bbuf + lofs);          \
    gload16(gB + (kk) + 16 * K, Bbuf + lofs + 512);    \
  } while (0)

  STAGE(as0, bs0, 0);
  __syncthreads();                      // drains prologue stage
  for (int k0 = 0; k0 < K; k0 += 64) {
    if (k0 + 32 < K) STAGE(as1, bs1, k0 + 32);     // issue early
    gemm_compute(as0, bs0, wm, wn, l16, g, acc);   // overlap with in-flight stage
    __syncthreads();                               // drains stage(k0+32)
    if (k0 + 64 < K) STAGE(as0, bs0, k0 + 64);
    gemm_compute(as1, bs1, wm, wn, l16, g, acc);
    __syncthreads();
  }
#undef STAGE

  // epilogue: bias + scatter to q/k/vT (bf16)
  int tbase = m0 & 1023;
  int b = m0 >> 10;
  int g4 = g * 4;
#pragma unroll
  for (int ni = 0; ni < 4; ++ni) {
    int n = n0 + wn + ni * 16 + l16;
    float bv = bias[n];
    int region = n / 768;
    int c = n - region * 768;
    int h = c >> 6, d = c & 63;
    int bh = b * 12 + h;
#pragma unroll
    for (int mi = 0; mi < 4; ++mi) {
      int t0 = tbase + wm + mi * 16 + g4;
      if (region == 2) {
        u16x4 pv;
#pragma unroll
        for (int r = 0; r < 4; ++r) pv[r] = f2bf(acc[mi][ni][r] + bv);
        *reinterpret_cast<u16x4*>(vTb + ((size_t)bh * 64 + d) * 1024 + t0) = pv;
      } else {
        u16* dst = (region == 0) ? qb : kb;
#pragma unroll
        for (int r = 0; r < 4; ++r)
          dst[((size_t)bh * 1024 + t0 + r) * 64 + d] = f2bf(acc[mi][ni][r] + bv);
      }
    }
  }
}

// ---------------- causal relu attention ----------------
// y[b,h,q,:] = sum_{k<=q} relu(scale * q.k) * v[k]
// Pipelined: loads(t+1) -> pack P(t)+LDS write -> QK^T(t+1) MFMAs (fill LDS
// write->read latency) -> LDS read P(t) -> PV(t).
__global__ __launch_bounds__(256) void attn_kernel(
    const u16* __restrict__ qb, const u16* __restrict__ kb,
    const u16* __restrict__ vTb, float* __restrict__ out) {
  __shared__ __align__(16) u16 plds[4][32 * 40];
  int lane = threadIdx.x & 63;
  int wave = threadIdx.x >> 6;
  int bh = blockIdx.x;                           // 0..95
  int q0 = (7 - blockIdx.y) * 128 + wave * 32;   // heaviest blocks first
  int b = bh / 12, h = bh - b * 12;
  const u16* Q  = qb  + (size_t)bh * 65536;
  const u16* Kp = kb  + (size_t)bh * 65536;
  const u16* Vt = vTb + (size_t)bh * 65536;
  int l16 = lane & 15, g = lane >> 4;
  u16* pw = &plds[wave][0];

  bf16x8 qf[2][2];
#pragma unroll
  for (int qi = 0; qi < 2; ++qi)
#pragma unroll
    for (int ks = 0; ks < 2; ++ks)
      qf[qi][ks] = __builtin_bit_cast(bf16x8,
          *reinterpret_cast<const u16x8*>(Q + (q0 + qi * 16 + l16) * 64 + ks * 32 + g * 8));

  f32x4 y[2][4];
#pragma unroll
  for (int mi = 0; mi < 2; ++mi)
#pragma unroll
    for (int ni = 0; ni < 4; ++ni) y[mi][ni] = (f32x4){0.f, 0.f, 0.f, 0.f};

  int ktmax = q0 >> 5;

  // prologue: K/V of tile 0, then S^T(0)
  u16x8 kn[4], vcur[4], vnxt[4];
#pragma unroll
  for (int kj = 0; kj < 2; ++kj)
#pragma unroll
    for (int ks = 0; ks < 2; ++ks)
      kn[kj * 2 + ks] = *reinterpret_cast<const u16x8*>(
          Kp + (kj * 16 + l16) * 64 + ks * 32 + g * 8);
#pragma unroll
  for (int ni = 0; ni < 4; ++ni)
    vcur[ni] = *reinterpret_cast<const u16x8*>(Vt + (ni * 16 + l16) * 1024 + g * 8);

  // S^T lane layout: q = qi*16+l16 (col), key = kj*16+g*4+r (row)
  f32x4 s2c[2][2];
#pragma unroll
  for (int kj = 0; kj < 2; ++kj)
#pragma unroll
    for (int qi = 0; qi < 2; ++qi) s2c[kj][qi] = (f32x4){0.f, 0.f, 0.f, 0.f};
#pragma unroll
  for (int ks = 0; ks < 2; ++ks)
#pragma unroll
    for (int kj = 0; kj < 2; ++kj) {
      bf16x8 kf = __builtin_bit_cast(bf16x8, kn[kj * 2 + ks]);
#pragma unroll
      for (int qi = 0; qi < 2; ++qi)
        s2c[kj][qi] = __builtin_amdgcn_mfma_f32_16x16x32_bf16(kf, qf[qi][ks], s2c[kj][qi], 0, 0, 0);
    }

  for (int kt = 0; kt <= ktmax; ++kt) {
    bool notlast = (kt < ktmax);

    // 1) issue next tile's K/V loads (consumed ~250cy later)
    if (notlast) {
      int kb2 = (kt + 1) << 5;
#pragma unroll
      for (int kj = 0; kj < 2; ++kj)
#pragma unroll
        for (int ks = 0; ks < 2; ++ks)
          kn[kj * 2 + ks] = *reinterpret_cast<const u16x8*>(
              Kp + (kb2 + kj * 16 + l16) * 64 + ks * 32 + g * 8);
#pragma unroll
      for (int ni = 0; ni < 4; ++ni)
        vnxt[ni] = *reinterpret_cast<const u16x8*>(Vt + (ni * 16 + l16) * 1024 + kb2 + g * 8);
    }

    // 2) pack P(t): scale, relu, diagonal mask; write LDS (b64 per (kj,qi))
    bool diag = !notlast;   // kbase == q0 on the last tile (q0 multiple of 32)
#pragma unroll
    for (int kj = 0; kj < 2; ++kj)
#pragma unroll
      for (int qi = 0; qi < 2; ++qi) {
        u16x4 pv;
#pragma unroll
        for (int r = 0; r < 4; ++r) {
          float v = fmaxf(s2c[kj][qi][r] * 0.125f, 0.f);
          if (diag && (kj * 16 + g * 4 + r > qi * 16 + l16)) v = 0.f;
          pv[r] = f2bf(v);
        }
        *reinterpret_cast<u16x4*>(pw + (qi * 16 + l16) * 40 + kj * 16 + g * 4) = pv;
      }

    __builtin_amdgcn_s_setprio(1);
    // 3) QK^T(t+1) — fills the LDS write->read latency window
    f32x4 s2n[2][2];
    if (notlast) {
#pragma unroll
      for (int kj = 0; kj < 2; ++kj)
#pragma unroll
        for (int qi = 0; qi < 2; ++qi) s2n[kj][qi] = (f32x4){0.f, 0.f, 0.f, 0.f};
#pragma unroll
      for (int ks = 0; ks < 2; ++ks)
#pragma unroll
        for (int kj = 0; kj < 2; ++kj) {
          bf16x8 kf = __builtin_bit_cast(bf16x8, kn[kj * 2 + ks]);
#pragma unroll
          for (int qi = 0; qi < 2; ++qi)
            s2n[kj][qi] = __builtin_amdgcn_mfma_f32_16x16x32_bf16(kf, qf[qi][ks], s2n[kj][qi], 0, 0, 0);
        }
    }

    // 4) read P(t), PV(t)
    bf16x8 pa[2];
#pragma unroll
    for (int mi = 0; mi < 2; ++mi)
      pa[mi] = __builtin_bit_cast(bf16x8,
          *reinterpret_cast<const u16x8*>(pw + (mi * 16 + l16) * 40 + g * 8));
#pragma unroll
    for (int ni = 0; ni < 4; ++ni) {
      bf16x8 vf = __builtin_bit_cast(bf16x8, vcur[ni]);
#pragma unroll
      for (int mi = 0; mi < 2; ++mi)
        y[mi][ni] = __builtin_amdgcn_mfma_f32_16x16x32_bf16(pa[mi], vf, y[mi][ni], 0, 0, 0);
    }
    __builtin_amdgcn_s_setprio(0);

    // 5) rotate
    if (notlast) {
#pragma unroll
      for (int kj = 0; kj < 2; ++kj)
#pragma unroll
        for (int qi = 0; qi < 2; ++qi) s2c[kj][qi] = s2n[kj][qi];
#pragma unroll
      for (int ni = 0; ni < 4; ++ni) vcur[ni] = vnxt[ni];
    }
  }

  // out[b, t, h*64+d] f32
  float* outp = out + (size_t)b * 1024 * 768 + (size_t)h * 64;
#pragma unroll
  for (int mi = 0; mi < 2; ++mi)
#pragma unroll
    for (int r = 0; r < 4; ++r) {
      int t = q0 + mi * 16 + g * 4 + r;
#pragma unroll
      for (int ni = 0; ni < 4; ++ni)
        outp[(size_t)t * 768 + ni * 16 + l16] = y[mi][ni][r];
    }
}

extern "C" void kernel_launch(void* const* d_in, const int* in_sizes, int n_in,
                              void* d_out, int out_size, void* d_ws, size_t ws_size,
                              hipStream_t stream) {
  const float* x    = (const float*)d_in[0];
  const float* W    = (const float*)d_in[1];
  const float* bias = (const float*)d_in[2];
  float* out = (float*)d_out;
  char* ws = (char*)d_ws;

  // ws layout (bytes): xb 12.58MB | WbT 3.54MB | qb 12.58MB | kb 12.58MB | vTb 12.58MB
  u16* xb  = (u16*)(ws);
  u16* WbT = (u16*)(ws + 12582912);
  u16* qb  = (u16*)(ws + 16121856);
  u16* kb  = (u16*)(ws + 28704768);
  u16* vTb = (u16*)(ws + 41287680);

  hipLaunchKernelGGL(cvt_x_kernel, dim3(3072), dim3(256), 0, stream, x, xb);
  hipLaunchKernelGGL(cvt_wT_kernel, dim3(9, 192), dim3(256), 0, stream, W, WbT);
  hipLaunchKernelGGL(gemm_qkv_kernel, dim3(64, 18), dim3(256), 0, stream,
                     xb, WbT, bias, qb, kb, vTb);
  hipLaunchKernelGGL(attn_kernel, dim3(96, 8), dim3(256), 0, stream, qb, kb, vTb, out);
}